// Round 15
// baseline (387.471 us; speedup 1.0000x reference)
//
#include <hip/hip_runtime.h>

// QKNorm MHA: B=2, L=2048, D=2048, H=16, hd=128.
// Round 15: micro pair — (1) GEMM phases issue staging DMA before ds_reads and
// drop the non-correctness mid-tile barrier (4->3 barriers/tile);
// (2) attention __launch_bounds__(256,3) for 3 blocks/CU (LDS 52KB*3<=160KB).
// Everything else identical to round 14.

#define DM   2048
#define HD   128
#define NH   16
#define LSEQ 2048
#define NB   2
#define MTOK 4096  // NB*LSEQ
#define QKVS 6144  // fused row stride

typedef __bf16 bf16x8 __attribute__((ext_vector_type(8)));
typedef float  f32x4  __attribute__((ext_vector_type(4)));

__device__ __forceinline__ unsigned short f2bf(float f) {
  unsigned u = __builtin_bit_cast(unsigned, f);
  u += 0x7fffu + ((u >> 16) & 1u);
  return (unsigned short)(u >> 16);
}
__device__ __forceinline__ unsigned packbf(float lo, float hi) {
  return (unsigned)f2bf(lo) | ((unsigned)f2bf(hi) << 16);
}
__device__ __forceinline__ float bf2f(unsigned short h) {
  unsigned u = ((unsigned)h) << 16;
  return __builtin_bit_cast(float, u);
}
__device__ __forceinline__ void gload16(const unsigned short* gc, unsigned short* l) {
  unsigned short* g = const_cast<unsigned short*>(gc);
  __builtin_amdgcn_global_load_lds((__attribute__((address_space(1))) void*)g,
                                   (__attribute__((address_space(3))) void*)l, 16, 0, 0);
}
__device__ __forceinline__ bf16x8 ld_frag(const void* p) {
  return __builtin_bit_cast(bf16x8, *(const uint4*)p);
}

// ------ fused f32->bf16 cast: x, Wq, Wk, Wv, Wo in one launch ------
__global__ void cvtall_k(const float* __restrict__ x, const float* __restrict__ Wq,
                         const float* __restrict__ Wk, const float* __restrict__ Wv,
                         const float* __restrict__ Wo, unsigned short* __restrict__ xb,
                         unsigned short* __restrict__ wqkv, unsigned short* __restrict__ wob) {
  const int xc = MTOK * DM / 8;    // 1048576
  const int per = DM * DM / 8;     // 524288
  int i = blockIdx.x * blockDim.x + threadIdx.x;
  const float* s;
  unsigned short* d;
  int j;
  if (i < xc) { s = x; d = xb; j = i; }
  else if (i < xc + per) { s = Wq; d = wqkv; j = i - xc; }
  else if (i < xc + 2 * per) { s = Wk; d = wqkv + DM * DM; j = i - xc - per; }
  else if (i < xc + 3 * per) { s = Wv; d = wqkv + 2 * DM * DM; j = i - xc - 2 * per; }
  else { s = Wo; d = wob; j = i - xc - 3 * per; }
  const float4* s4 = (const float4*)s;
  float4 a = s4[2 * j], b = s4[2 * j + 1];
  uint4 o;
  o.x = packbf(a.x, a.y);
  o.y = packbf(a.z, a.w);
  o.z = packbf(b.x, b.y);
  o.w = packbf(b.z, b.w);
  ((uint4*)d)[j] = o;
}

// ========== GEMM BM=128 BN=256 BK=64, fine-phase (stage-first, 3 bar/tile) ==========
template <int OUT_BF16, int QKVMODE>
__global__ __launch_bounds__(512) void gemmv5_bt(
    const unsigned short* __restrict__ A, const unsigned short* __restrict__ Bm,
    const float* __restrict__ b0, const float* __restrict__ b1,
    const float* __restrict__ b2, void* __restrict__ Cv,
    unsigned short* __restrict__ Vt, int M, int N, int K) {
  __shared__ unsigned short Ab[2][128 * 64];  // 16 KiB each
  __shared__ unsigned short Bb[3][256 * 64];  // 32 KiB each (128 KiB total)
  const int tid = threadIdx.x, wave = tid >> 6, lane = tid & 63;
  const int l15 = lane & 15, l4 = lane >> 4;
  const int wr = wave >> 2, wc = wave & 3;

  const int np = N >> 8;
  int n_id, m_id;
  if ((np & 7) == 0) {
    int cpx = np >> 3;
    int xcd = blockIdx.x & 7, r = blockIdx.x >> 3;
    n_id = xcd * cpx + r % cpx;
    m_id = r / cpx;
  } else {
    n_id = blockIdx.x % np;
    m_id = blockIdx.x / np;
  }
  const size_t ra0 = (size_t)m_id * 128, rb0 = (size_t)n_id * 256;
  const int NT = K >> 6;

  const int arow = tid >> 3, acg = (tid & 7) ^ (arow & 7);
  int brow[2], bcg[2];
#pragma unroll
  for (int j = 0; j < 2; j++) {
    int c = j * 512 + tid;
    brow[j] = c >> 3;
    bcg[j] = (c & 7) ^ (brow[j] & 7);
  }

#define STAGE_A(kt, slot)                                                       \
  {                                                                             \
    _Pragma("unroll") for (int h = 0; h < 2; h++) {                             \
      gload16(A + (ra0 + h * 64 + arow) * (size_t)K + ((kt) << 6) + acg * 8,    \
              &Ab[slot][(h * 512 + wave * 64) * 8]);                            \
    }                                                                           \
  }

#define STAGE_B(kt, slot, half)                                                 \
  {                                                                             \
    _Pragma("unroll") for (int j = 0; j < 2; j++) {                             \
      gload16(Bm + (rb0 + (half)*128 + brow[j]) * (size_t)K + ((kt) << 6) +     \
                  bcg[j] * 8,                                                   \
              &Bb[slot][((half)*1024 + j * 512 + wave * 64) * 8]);              \
    }                                                                           \
  }

#define LDA(kh, slot)                                                           \
  _Pragma("unroll") for (int mi = 0; mi < 4; mi++) {                            \
    int row = wr * 64 + mi * 16 + l15;                                          \
    int cl = ((kh)*4 + l4) ^ (row & 7);                                         \
    af[mi] = ld_frag((char*)&Ab[slot][0] + row * 128 + cl * 16);                \
  }

#define LDB(kh, slot)                                                           \
  _Pragma("unroll") for (int n = 0; n < 4; n++) {                               \
    int row = wc * 64 + n * 16 + l15;                                           \
    int cl = ((kh)*4 + l4) ^ (row & 7);                                         \
    bf_[n] = ld_frag((char*)&Bb[slot][0] + row * 128 + cl * 16);                \
  }

#define MMA()                                                                   \
  __builtin_amdgcn_s_setprio(1);                                                \
  _Pragma("unroll") for (int mi = 0; mi < 4; mi++)                              \
      _Pragma("unroll") for (int n = 0; n < 4; n++)                             \
          acc[mi][n] = __builtin_amdgcn_mfma_f32_16x16x32_bf16(                 \
              af[mi], bf_[n], acc[mi][n], 0, 0, 0);                             \
  __builtin_amdgcn_s_setprio(0);

  f32x4 acc[4][4] = {};
  bf16x8 af[4], bf_[4];

  STAGE_A(0, 0)
  STAGE_B(0, 0, 0)
  STAGE_B(0, 0, 1)
  STAGE_B(1, 1, 0)
  STAGE_B(1, 1, 1)
  asm volatile("s_waitcnt vmcnt(4)" ::: "memory");
  __builtin_amdgcn_s_barrier();
  __builtin_amdgcn_sched_barrier(0);

  int bsc = 0;
  for (int T = 0; T < NT; ++T) {
    const int ad = T & 1, an = ad ^ 1;
    int bs2 = bsc + 2;
    if (bs2 >= 3) bs2 -= 3;
    const bool pa = (T + 1 < NT), pb = (T + 2 < NT);

    // ---- phase 0: stage A(T+1) first (DMA in flight), then kh=0 reads ----
    if (pa) STAGE_A(T + 1, an)
    LDB(0, bsc)
    LDA(0, ad)
    __builtin_amdgcn_s_barrier();
    asm volatile("s_waitcnt lgkmcnt(0)" ::: "memory");
    __builtin_amdgcn_sched_barrier(0);
    MMA()
    // (mid-tile barrier removed: ph1 reads same stable slots, stages write
    //  slots not read this tile — no hazard)
    // ---- phase 1: stage B(T+2) first, then kh=1 reads ----
    if (pb) {
      STAGE_B(T + 2, bs2, 0)
      STAGE_B(T + 2, bs2, 1)
    }
    LDB(1, bsc)
    LDA(1, ad)
    __builtin_amdgcn_s_barrier();
    asm volatile("s_waitcnt lgkmcnt(0)" ::: "memory");
    __builtin_amdgcn_sched_barrier(0);
    MMA()
    if (pa) {
      if (pb) {
        asm volatile("s_waitcnt vmcnt(4)" ::: "memory");  // A(T+1)+B(T+1) in
      } else {
        asm volatile("s_waitcnt vmcnt(0)" ::: "memory");
      }
    }
    __builtin_amdgcn_s_barrier();
    __builtin_amdgcn_sched_barrier(0);
    bsc = (bsc == 2) ? 0 : bsc + 1;
  }

  // ---------------- epilogue ----------------
  const int row0 = m_id * 128 + wr * 64;
  const int col0 = n_id * 256 + wc * 64;

  float bv[4];
#pragma unroll
  for (int n = 0; n < 4; n++) {
    int col = col0 + n * 16 + l15;
    if (QKVMODE)
      bv[n] = col < 2048 ? b0[col] : (col < 4096 ? b1[col - 2048] : b2[col - 4096]);
    else
      bv[n] = b0[col];
  }

  if (QKVMODE && n_id >= 16) {
    const int bblk = row0 >> 11;
#pragma unroll
    for (int n = 0; n < 4; n++) {
      int vcol = col0 + n * 16 + l15 - 4096;
      int hh = vcol >> 7, dd = vcol & 127;
      size_t vbase = ((size_t)(bblk * 16 + hh) * 128 + dd) * (size_t)LSEQ;
#pragma unroll
      for (int mi = 0; mi < 4; mi++) {
        int rowb = row0 + mi * 16 + l4 * 4;
        unsigned short t4[4];
#pragma unroll
        for (int r = 0; r < 4; r++) t4[r] = f2bf(acc[mi][n][r] + bv[n]);
        *(uint2*)(Vt + vbase + (rowb & (LSEQ - 1))) = *(const uint2*)t4;
      }
    }
    return;
  }

  if (QKVMODE && n_id < 16) {
    float* sp = (float*)&Ab[0][0];  // [8 waves][64 rows]
    __syncthreads();
#pragma unroll
    for (int mi = 0; mi < 4; mi++) {
#pragma unroll
      for (int r = 0; r < 4; r++) {
        float ss = 0.f;
#pragma unroll
        for (int n = 0; n < 4; n++) {
          float v = acc[mi][n][r] + bv[n];
          ss += v * v;
        }
        ss += __shfl_xor(ss, 1);
        ss += __shfl_xor(ss, 2);
        ss += __shfl_xor(ss, 4);
        ss += __shfl_xor(ss, 8);
        if (l15 == 0) sp[wave * 64 + mi * 16 + l4 * 4 + r] = ss;
      }
    }
    __syncthreads();
#pragma unroll
    for (int mi = 0; mi < 4; mi++) {
#pragma unroll
      for (int r = 0; r < 4; r++) {
        int idx = mi * 16 + l4 * 4 + r;
        float ss = sp[wave * 64 + idx] + sp[(wave ^ 1) * 64 + idx];
        float inv = 1.0f / (sqrtf(ss) + 1e-6f);
        int row = row0 + mi * 16 + l4 * 4 + r;
#pragma unroll
        for (int n = 0; n < 4; n++) {
          int col = col0 + n * 16 + l15;
          ((unsigned short*)Cv)[(size_t)row * N + col] = f2bf((acc[mi][n][r] + bv[n]) * inv);
        }
      }
    }
    return;
  }

#pragma unroll
  for (int n = 0; n < 4; n++) {
    int col = col0 + n * 16 + l15;
#pragma unroll
    for (int mi = 0; mi < 4; mi++) {
      int rowb = row0 + mi * 16 + l4 * 4;
#pragma unroll
      for (int r = 0; r < 4; r++) {
        float v = acc[mi][n][r] + bv[n];
        if (OUT_BF16)
          ((unsigned short*)Cv)[(size_t)(rowb + r) * N + col] = f2bf(v);
        else
          ((float*)Cv)[(size_t)(rowb + r) * N + col] = v;
      }
    }
  }
#undef STAGE_A
#undef STAGE_B
#undef LDA
#undef LDB
#undef MMA
}

// ---------------- attention v5: full KV range, direct O output ----------------
// grid 512, 3 blocks/CU target (LDS 52KB, VGPR capped 170 via launch_bounds).
__global__ __launch_bounds__(256, 3) void attn5_k(
    const unsigned short* __restrict__ QKV, const unsigned short* __restrict__ Vt,
    unsigned short* __restrict__ Ao) {
  __shared__ __align__(16) unsigned short Ks[2][32 * 128];  // pitch 256B, XOR (row&7)<<4
  __shared__ __align__(16) unsigned short Vs[2][128 * 40];  // pitch 80B, no XOR

  const int id = blockIdx.x;
  const int xcd = id & 7, sl = id >> 3;      // sl in 0..63
  const int bh = xcd * 4 + (sl >> 4);
  const int qb = sl & 15;
  const int b = bh >> 4, h = bh & 15;
  const int q0 = qb * 128;
  const int tid = threadIdx.x, wave = tid >> 6, lane = tid & 63;
  const int l15 = lane & 15, l4 = lane >> 4;
  const float scale = 0.08838834764831845f;  // 1/sqrt(128)

  bf16x8 qf[2][4];
#pragma unroll
  for (int rg = 0; rg < 2; rg++) {
    const unsigned short* qp =
        QKV + ((size_t)(b * LSEQ + q0 + wave * 32 + rg * 16 + l15)) * QKVS + h * HD + l4 * 8;
#pragma unroll
    for (int kk = 0; kk < 4; kk++) qf[rg][kk] = ld_frag(qp + kk * 32);
  }

  f32x4 oacc[2][8] = {};
  float den[2] = {0.f, 0.f};
  uint4 pk[2], pv[2];

  const unsigned short* Kb = QKV + ((size_t)(b * LSEQ)) * QKVS + 2048 + h * HD;
  const unsigned short* Vb = Vt + ((size_t)bh * HD) * LSEQ;
  const int kr0 = tid >> 4, kc = tid & 15;
  const int vr0 = tid >> 2, vc = tid & 3;
  const int srcA = ((l4 * 2) & 3) * 16 + l15;
  const int srcB = ((l4 * 2 + 1) & 3) * 16 + l15;
  const bool hiSel = (l4 >= 2);

#pragma unroll
  for (int i = 0; i < 2; i++) {
    pk[i] = *(const uint4*)(Kb + (size_t)(kr0 + i * 16) * QKVS + kc * 8);
    pv[i] = *(const uint4*)(Vb + (size_t)(vr0 + i * 64) * LSEQ + vc * 8);
  }
#pragma unroll
  for (int i = 0; i < 2; i++) {
    int kr = kr0 + i * 16;
    *(uint4*)((char*)&Ks[0][0] + kr * 256 + ((kc ^ (kr & 7)) << 4)) = pk[i];
    int vr = vr0 + i * 64;
    *(uint4*)((char*)&Vs[0][0] + vr * 80 + vc * 16) = pv[i];
  }

  for (int t = 0; t < 64; t++) {
    const int cur = t & 1;
    __syncthreads();
    if (t + 1 < 64) {
      const int kvn = (t + 1) * 32;
#pragma unroll
      for (int i = 0; i < 2; i++) {
        pk[i] = *(const uint4*)(Kb + (size_t)(kvn + kr0 + i * 16) * QKVS + kc * 8);
        pv[i] = *(const uint4*)(Vb + (size_t)(vr0 + i * 64) * LSEQ + kvn + vc * 8);
      }
    }

    f32x4 sacc[2][2] = {};
    char* ksb = (char*)&Ks[cur][0];
    __builtin_amdgcn_s_setprio(1);
#pragma unroll
    for (int ni = 0; ni < 2; ni++) {
#pragma unroll
      for (int kk = 0; kk < 4; kk++) {
        bf16x8 kf = ld_frag(ksb + (ni * 16 + l15) * 256 + (((kk * 4 + l4) ^ (l15 & 7)) << 4));
        sacc[0][ni] = __builtin_amdgcn_mfma_f32_16x16x32_bf16(kf, qf[0][kk], sacc[0][ni], 0, 0, 0);
        sacc[1][ni] = __builtin_amdgcn_mfma_f32_16x16x32_bf16(kf, qf[1][kk], sacc[1][ni], 0, 0, 0);
      }
    }
    __builtin_amdgcn_s_setprio(0);

    bf16x8 pa[2];
#pragma unroll
    for (int rg = 0; rg < 2; rg++) {
      float pe[4], po[4];
#pragma unroll
      for (int r = 0; r < 4; r++) {
        pe[r] = __expf(sacc[rg][0][r] * scale);
        po[r] = __expf(sacc[rg][1][r] * scale);
      }
      den[rg] += (pe[0] + pe[1]) + (pe[2] + pe[3]) + (po[0] + po[1]) + (po[2] + po[3]);
      unsigned c0e = packbf(pe[0], pe[1]), c1e = packbf(pe[2], pe[3]);
      unsigned c0o = packbf(po[0], po[1]), c1o = packbf(po[2], po[3]);
      unsigned a0 = __shfl(c0e, srcA), a1 = __shfl(c0o, srcA);
      unsigned b0 = __shfl(c1e, srcA), b1 = __shfl(c1o, srcA);
      unsigned c0 = __shfl(c0e, srcB), c1 = __shfl(c0o, srcB);
      unsigned d0_ = __shfl(c1e, srcB), d1 = __shfl(c1o, srcB);
      uint4 paw;
      paw.x = hiSel ? a1 : a0;
      paw.y = hiSel ? b1 : b0;
      paw.z = hiSel ? c1 : c0;
      paw.w = hiSel ? d1 : d0_;
      pa[rg] = __builtin_bit_cast(bf16x8, paw);
    }

    char* vsb = (char*)&Vs[cur][0];
    __builtin_amdgcn_s_setprio(1);
#pragma unroll
    for (int d0 = 0; d0 < 8; d0++) {
      bf16x8 vf = ld_frag(vsb + (d0 * 16 + l15) * 80 + l4 * 16);
      oacc[0][d0] = __builtin_amdgcn_mfma_f32_16x16x32_bf16(pa[0], vf, oacc[0][d0], 0, 0, 0);
      oacc[1][d0] = __builtin_amdgcn_mfma_f32_16x16x32_bf16(pa[1], vf, oacc[1][d0], 0, 0, 0);
    }
    __builtin_amdgcn_s_setprio(0);

    if (t + 1 < 64) {
      char* ksn = (char*)&Ks[cur ^ 1][0];
      char* vsn = (char*)&Vs[cur ^ 1][0];
#pragma unroll
      for (int i = 0; i < 2; i++) {
        int kr = kr0 + i * 16;
        *(uint4*)(ksn + kr * 256 + ((kc ^ (kr & 7)) << 4)) = pk[i];
        int vr = vr0 + i * 64;
        *(uint4*)(vsn + vr * 80 + vc * 16) = pv[i];
      }
    }
  }

  // den: full sum for q-row l15 after xor-16/32; move to l4*4+r rows via shfl
  float dinv[2][4];
#pragma unroll
  for (int rg = 0; rg < 2; rg++) {
    float sd = den[rg];
    sd += __shfl_xor(sd, 16);
    sd += __shfl_xor(sd, 32);
#pragma unroll
    for (int r = 0; r < 4; r++) dinv[rg][r] = 1.0f / __shfl(sd, l4 * 4 + r);
  }
#pragma unroll
  for (int rg = 0; rg < 2; rg++)
#pragma unroll
    for (int d0 = 0; d0 < 8; d0++)
#pragma unroll
      for (int r = 0; r < 4; r++) {
        int token = b * LSEQ + q0 + wave * 32 + rg * 16 + l4 * 4 + r;
        Ao[(size_t)token * DM + h * HD + d0 * 16 + l15] =
            f2bf(oacc[rg][d0][r] * dinv[rg][r]);
      }
}

extern "C" void kernel_launch(void* const* d_in, const int* in_sizes, int n_in,
                              void* d_out, int out_size, void* d_ws, size_t ws_size,
                              hipStream_t stream) {
  const float* x  = (const float*)d_in[0];
  const float* Wq = (const float*)d_in[1];
  const float* bq = (const float*)d_in[2];
  const float* Wk = (const float*)d_in[3];
  const float* bk = (const float*)d_in[4];
  const float* Wv = (const float*)d_in[5];
  const float* bv = (const float*)d_in[6];
  const float* Wo = (const float*)d_in[7];
  const float* bo = (const float*)d_in[8];

  char* ws = (char*)d_ws;
  unsigned short* xb   = (unsigned short*)(ws + 0);          // [0,16M): x bf16 -> attn out
  unsigned short* wqkv = (unsigned short*)(ws + 16777216);   // [16M,40M): Wq|Wk|Wv bf16
  unsigned short* wob  = (unsigned short*)(ws + 41943040);   // [40M,48M): Wo bf16
  unsigned short* qkv  = (unsigned short*)(ws + 50364416);   // 48 MB region (q|k cols used)
  unsigned short* vt   = (unsigned short*)(ws + 100696064);  // 16.8 MB (transposed V)
  unsigned short* ao   = xb;                                  // x dead after QKV gemm

  // 1. all casts in one launch
  cvtall_k<<<12288, 256, 0, stream>>>(x, Wq, Wk, Wv, Wo, xb, wqkv, wob);

  // 2. fused QKV projection + q/k-norm + transposed V (768 blocks, 3.0 rounds)
  gemmv5_bt<1, 1><<<(MTOK / 128) * (QKVS / 256), 512, 0, stream>>>(
      xb, wqkv, bq, bk, bv, qkv, vt, MTOK, QKVS, DM);

  // 3. attention (full KV per block, grid 512, direct O)
  attn5_k<<<512, 256, 0, stream>>>(qkv, vt, ao);

  // 4. output projection (f32 out, 256 blocks = 1.0 round)
  gemmv5_bt<0, 0><<<(MTOK / 128) * (DM / 256), 512, 0, stream>>>(
      ao, wob, bo, bo, bo, (float*)d_out, nullptr, MTOK, DM, DM);
}

// Round 16
// 283.563 us; speedup vs baseline: 1.3664x; 1.3664x over previous
//
#include <hip/hip_runtime.h>

// QKNorm MHA: B=2, L=2048, D=2048, H=16, hd=128.
// Round 16: clean revert to round-14 (session best, 284 us). Round-15's micro
// pair (barrier removal + stage-first + attn launch_bounds(256,3)) regressed
// GEMM 134->185 us — the mid-tile barrier enforces the all-waves-MFMA cadence
// (m141/m196 lesson: the barrier IS the interleave mechanism).

#define DM   2048
#define HD   128
#define NH   16
#define LSEQ 2048
#define NB   2
#define MTOK 4096  // NB*LSEQ
#define QKVS 6144  // fused row stride

typedef __bf16 bf16x8 __attribute__((ext_vector_type(8)));
typedef float  f32x4  __attribute__((ext_vector_type(4)));

__device__ __forceinline__ unsigned short f2bf(float f) {
  unsigned u = __builtin_bit_cast(unsigned, f);
  u += 0x7fffu + ((u >> 16) & 1u);
  return (unsigned short)(u >> 16);
}
__device__ __forceinline__ unsigned packbf(float lo, float hi) {
  return (unsigned)f2bf(lo) | ((unsigned)f2bf(hi) << 16);
}
__device__ __forceinline__ float bf2f(unsigned short h) {
  unsigned u = ((unsigned)h) << 16;
  return __builtin_bit_cast(float, u);
}
__device__ __forceinline__ void gload16(const unsigned short* gc, unsigned short* l) {
  unsigned short* g = const_cast<unsigned short*>(gc);
  __builtin_amdgcn_global_load_lds((__attribute__((address_space(1))) void*)g,
                                   (__attribute__((address_space(3))) void*)l, 16, 0, 0);
}
__device__ __forceinline__ bf16x8 ld_frag(const void* p) {
  return __builtin_bit_cast(bf16x8, *(const uint4*)p);
}

// ------ fused f32->bf16 cast: x, Wq, Wk, Wv, Wo in one launch ------
__global__ void cvtall_k(const float* __restrict__ x, const float* __restrict__ Wq,
                         const float* __restrict__ Wk, const float* __restrict__ Wv,
                         const float* __restrict__ Wo, unsigned short* __restrict__ xb,
                         unsigned short* __restrict__ wqkv, unsigned short* __restrict__ wob) {
  const int xc = MTOK * DM / 8;    // 1048576
  const int per = DM * DM / 8;     // 524288
  int i = blockIdx.x * blockDim.x + threadIdx.x;
  const float* s;
  unsigned short* d;
  int j;
  if (i < xc) { s = x; d = xb; j = i; }
  else if (i < xc + per) { s = Wq; d = wqkv; j = i - xc; }
  else if (i < xc + 2 * per) { s = Wk; d = wqkv + DM * DM; j = i - xc - per; }
  else if (i < xc + 3 * per) { s = Wv; d = wqkv + 2 * DM * DM; j = i - xc - 2 * per; }
  else { s = Wo; d = wob; j = i - xc - 3 * per; }
  const float4* s4 = (const float4*)s;
  float4 a = s4[2 * j], b = s4[2 * j + 1];
  uint4 o;
  o.x = packbf(a.x, a.y);
  o.y = packbf(a.z, a.w);
  o.z = packbf(b.x, b.y);
  o.w = packbf(b.z, b.w);
  ((uint4*)d)[j] = o;
}

// ========== GEMM BM=128 BN=256 BK=64, fine-phase, counted vmcnt (r13/r14) ==========
template <int OUT_BF16, int QKVMODE>
__global__ __launch_bounds__(512) void gemmv5_bt(
    const unsigned short* __restrict__ A, const unsigned short* __restrict__ Bm,
    const float* __restrict__ b0, const float* __restrict__ b1,
    const float* __restrict__ b2, void* __restrict__ Cv,
    unsigned short* __restrict__ Vt, int M, int N, int K) {
  __shared__ unsigned short Ab[2][128 * 64];  // 16 KiB each
  __shared__ unsigned short Bb[3][256 * 64];  // 32 KiB each (128 KiB total)
  const int tid = threadIdx.x, wave = tid >> 6, lane = tid & 63;
  const int l15 = lane & 15, l4 = lane >> 4;
  const int wr = wave >> 2, wc = wave & 3;

  const int np = N >> 8;
  int n_id, m_id;
  if ((np & 7) == 0) {
    int cpx = np >> 3;
    int xcd = blockIdx.x & 7, r = blockIdx.x >> 3;
    n_id = xcd * cpx + r % cpx;
    m_id = r / cpx;
  } else {
    n_id = blockIdx.x % np;
    m_id = blockIdx.x / np;
  }
  const size_t ra0 = (size_t)m_id * 128, rb0 = (size_t)n_id * 256;
  const int NT = K >> 6;

  const int arow = tid >> 3, acg = (tid & 7) ^ (arow & 7);
  int brow[2], bcg[2];
#pragma unroll
  for (int j = 0; j < 2; j++) {
    int c = j * 512 + tid;
    brow[j] = c >> 3;
    bcg[j] = (c & 7) ^ (brow[j] & 7);
  }

#define STAGE_A(kt, slot)                                                       \
  {                                                                             \
    _Pragma("unroll") for (int h = 0; h < 2; h++) {                             \
      gload16(A + (ra0 + h * 64 + arow) * (size_t)K + ((kt) << 6) + acg * 8,    \
              &Ab[slot][(h * 512 + wave * 64) * 8]);                            \
    }                                                                           \
  }

#define STAGE_B(kt, slot, half)                                                 \
  {                                                                             \
    _Pragma("unroll") for (int j = 0; j < 2; j++) {                             \
      gload16(Bm + (rb0 + (half)*128 + brow[j]) * (size_t)K + ((kt) << 6) +     \
                  bcg[j] * 8,                                                   \
              &Bb[slot][((half)*1024 + j * 512 + wave * 64) * 8]);              \
    }                                                                           \
  }

#define LDA(kh, slot)                                                           \
  _Pragma("unroll") for (int mi = 0; mi < 4; mi++) {                            \
    int row = wr * 64 + mi * 16 + l15;                                          \
    int cl = ((kh)*4 + l4) ^ (row & 7);                                         \
    af[mi] = ld_frag((char*)&Ab[slot][0] + row * 128 + cl * 16);                \
  }

#define LDB(kh, slot)                                                           \
  _Pragma("unroll") for (int n = 0; n < 4; n++) {                               \
    int row = wc * 64 + n * 16 + l15;                                           \
    int cl = ((kh)*4 + l4) ^ (row & 7);                                         \
    bf_[n] = ld_frag((char*)&Bb[slot][0] + row * 128 + cl * 16);                \
  }

#define MMA()                                                                   \
  __builtin_amdgcn_s_setprio(1);                                                \
  _Pragma("unroll") for (int mi = 0; mi < 4; mi++)                              \
      _Pragma("unroll") for (int n = 0; n < 4; n++)                             \
          acc[mi][n] = __builtin_amdgcn_mfma_f32_16x16x32_bf16(                 \
              af[mi], bf_[n], acc[mi][n], 0, 0, 0);                             \
  __builtin_amdgcn_s_setprio(0);

  f32x4 acc[4][4] = {};
  bf16x8 af[4], bf_[4];

  STAGE_A(0, 0)
  STAGE_B(0, 0, 0)
  STAGE_B(0, 0, 1)
  STAGE_B(1, 1, 0)
  STAGE_B(1, 1, 1)
  asm volatile("s_waitcnt vmcnt(4)" ::: "memory");
  __builtin_amdgcn_s_barrier();
  __builtin_amdgcn_sched_barrier(0);

  int bsc = 0;
  for (int T = 0; T < NT; ++T) {
    const int ad = T & 1, an = ad ^ 1;
    int bs2 = bsc + 2;
    if (bs2 >= 3) bs2 -= 3;
    const bool pa = (T + 1 < NT), pb = (T + 2 < NT);

    LDB(0, bsc)
    LDA(0, ad)
    if (pa) STAGE_A(T + 1, an)
    __builtin_amdgcn_s_barrier();
    asm volatile("s_waitcnt lgkmcnt(0)" ::: "memory");
    __builtin_amdgcn_sched_barrier(0);
    MMA()
    __builtin_amdgcn_s_barrier();
    LDB(1, bsc)
    LDA(1, ad)
    if (pb) {
      STAGE_B(T + 2, bs2, 0)
      STAGE_B(T + 2, bs2, 1)
    }
    __builtin_amdgcn_s_barrier();
    asm volatile("s_waitcnt lgkmcnt(0)" ::: "memory");
    __builtin_amdgcn_sched_barrier(0);
    MMA()
    if (pa) {
      if (pb) {
        asm volatile("s_waitcnt vmcnt(4)" ::: "memory");
      } else {
        asm volatile("s_waitcnt vmcnt(0)" ::: "memory");
      }
    }
    __builtin_amdgcn_s_barrier();
    __builtin_amdgcn_sched_barrier(0);
    bsc = (bsc == 2) ? 0 : bsc + 1;
  }

  // ---------------- epilogue ----------------
  const int row0 = m_id * 128 + wr * 64;
  const int col0 = n_id * 256 + wc * 64;

  float bv[4];
#pragma unroll
  for (int n = 0; n < 4; n++) {
    int col = col0 + n * 16 + l15;
    if (QKVMODE)
      bv[n] = col < 2048 ? b0[col] : (col < 4096 ? b1[col - 2048] : b2[col - 4096]);
    else
      bv[n] = b0[col];
  }

  if (QKVMODE && n_id >= 16) {
    const int bblk = row0 >> 11;
#pragma unroll
    for (int n = 0; n < 4; n++) {
      int vcol = col0 + n * 16 + l15 - 4096;
      int hh = vcol >> 7, dd = vcol & 127;
      size_t vbase = ((size_t)(bblk * 16 + hh) * 128 + dd) * (size_t)LSEQ;
#pragma unroll
      for (int mi = 0; mi < 4; mi++) {
        int rowb = row0 + mi * 16 + l4 * 4;
        unsigned short t4[4];
#pragma unroll
        for (int r = 0; r < 4; r++) t4[r] = f2bf(acc[mi][n][r] + bv[n]);
        *(uint2*)(Vt + vbase + (rowb & (LSEQ - 1))) = *(const uint2*)t4;
      }
    }
    return;
  }

  if (QKVMODE && n_id < 16) {
    float* sp = (float*)&Ab[0][0];  // [8 waves][64 rows]
    __syncthreads();
#pragma unroll
    for (int mi = 0; mi < 4; mi++) {
#pragma unroll
      for (int r = 0; r < 4; r++) {
        float ss = 0.f;
#pragma unroll
        for (int n = 0; n < 4; n++) {
          float v = acc[mi][n][r] + bv[n];
          ss += v * v;
        }
        ss += __shfl_xor(ss, 1);
        ss += __shfl_xor(ss, 2);
        ss += __shfl_xor(ss, 4);
        ss += __shfl_xor(ss, 8);
        if (l15 == 0) sp[wave * 64 + mi * 16 + l4 * 4 + r] = ss;
      }
    }
    __syncthreads();
#pragma unroll
    for (int mi = 0; mi < 4; mi++) {
#pragma unroll
      for (int r = 0; r < 4; r++) {
        int idx = mi * 16 + l4 * 4 + r;
        float ss = sp[wave * 64 + idx] + sp[(wave ^ 1) * 64 + idx];
        float inv = 1.0f / (sqrtf(ss) + 1e-6f);
        int row = row0 + mi * 16 + l4 * 4 + r;
#pragma unroll
        for (int n = 0; n < 4; n++) {
          int col = col0 + n * 16 + l15;
          ((unsigned short*)Cv)[(size_t)row * N + col] = f2bf((acc[mi][n][r] + bv[n]) * inv);
        }
      }
    }
    return;
  }

#pragma unroll
  for (int n = 0; n < 4; n++) {
    int col = col0 + n * 16 + l15;
#pragma unroll
    for (int mi = 0; mi < 4; mi++) {
      int rowb = row0 + mi * 16 + l4 * 4;
#pragma unroll
      for (int r = 0; r < 4; r++) {
        float v = acc[mi][n][r] + bv[n];
        if (OUT_BF16)
          ((unsigned short*)Cv)[(size_t)(rowb + r) * N + col] = f2bf(v);
        else
          ((float*)Cv)[(size_t)(rowb + r) * N + col] = v;
      }
    }
  }
#undef STAGE_A
#undef STAGE_B
#undef LDA
#undef LDB
#undef MMA
}

// ---------------- attention v5: full KV range, direct O output ----------------
// grid 512: xcd=id&7 owns 4 heads; per head 16 qb. 4 waves x 32 q-rows,
// KVBLK=32 double-buffered, swapped QK^T, register P. Writes O=num/den (bf16).
__global__ __launch_bounds__(256) void attn5_k(
    const unsigned short* __restrict__ QKV, const unsigned short* __restrict__ Vt,
    unsigned short* __restrict__ Ao) {
  __shared__ __align__(16) unsigned short Ks[2][32 * 128];  // pitch 256B, XOR (row&7)<<4
  __shared__ __align__(16) unsigned short Vs[2][128 * 40];  // pitch 80B, no XOR

  const int id = blockIdx.x;
  const int xcd = id & 7, sl = id >> 3;      // sl in 0..63
  const int bh = xcd * 4 + (sl >> 4);
  const int qb = sl & 15;
  const int b = bh >> 4, h = bh & 15;
  const int q0 = qb * 128;
  const int tid = threadIdx.x, wave = tid >> 6, lane = tid & 63;
  const int l15 = lane & 15, l4 = lane >> 4;
  const float scale = 0.08838834764831845f;  // 1/sqrt(128)

  bf16x8 qf[2][4];
#pragma unroll
  for (int rg = 0; rg < 2; rg++) {
    const unsigned short* qp =
        QKV + ((size_t)(b * LSEQ + q0 + wave * 32 + rg * 16 + l15)) * QKVS + h * HD + l4 * 8;
#pragma unroll
    for (int kk = 0; kk < 4; kk++) qf[rg][kk] = ld_frag(qp + kk * 32);
  }

  f32x4 oacc[2][8] = {};
  float den[2] = {0.f, 0.f};
  uint4 pk[2], pv[2];

  const unsigned short* Kb = QKV + ((size_t)(b * LSEQ)) * QKVS + 2048 + h * HD;
  const unsigned short* Vb = Vt + ((size_t)bh * HD) * LSEQ;
  const int kr0 = tid >> 4, kc = tid & 15;
  const int vr0 = tid >> 2, vc = tid & 3;
  const int srcA = ((l4 * 2) & 3) * 16 + l15;
  const int srcB = ((l4 * 2 + 1) & 3) * 16 + l15;
  const bool hiSel = (l4 >= 2);

#pragma unroll
  for (int i = 0; i < 2; i++) {
    pk[i] = *(const uint4*)(Kb + (size_t)(kr0 + i * 16) * QKVS + kc * 8);
    pv[i] = *(const uint4*)(Vb + (size_t)(vr0 + i * 64) * LSEQ + vc * 8);
  }
#pragma unroll
  for (int i = 0; i < 2; i++) {
    int kr = kr0 + i * 16;
    *(uint4*)((char*)&Ks[0][0] + kr * 256 + ((kc ^ (kr & 7)) << 4)) = pk[i];
    int vr = vr0 + i * 64;
    *(uint4*)((char*)&Vs[0][0] + vr * 80 + vc * 16) = pv[i];
  }

  for (int t = 0; t < 64; t++) {
    const int cur = t & 1;
    __syncthreads();
    if (t + 1 < 64) {
      const int kvn = (t + 1) * 32;
#pragma unroll
      for (int i = 0; i < 2; i++) {
        pk[i] = *(const uint4*)(Kb + (size_t)(kvn + kr0 + i * 16) * QKVS + kc * 8);
        pv[i] = *(const uint4*)(Vb + (size_t)(vr0 + i * 64) * LSEQ + kvn + vc * 8);
      }
    }

    f32x4 sacc[2][2] = {};
    char* ksb = (char*)&Ks[cur][0];
    __builtin_amdgcn_s_setprio(1);
#pragma unroll
    for (int ni = 0; ni < 2; ni++) {
#pragma unroll
      for (int kk = 0; kk < 4; kk++) {
        bf16x8 kf = ld_frag(ksb + (ni * 16 + l15) * 256 + (((kk * 4 + l4) ^ (l15 & 7)) << 4));
        sacc[0][ni] = __builtin_amdgcn_mfma_f32_16x16x32_bf16(kf, qf[0][kk], sacc[0][ni], 0, 0, 0);
        sacc[1][ni] = __builtin_amdgcn_mfma_f32_16x16x32_bf16(kf, qf[1][kk], sacc[1][ni], 0, 0, 0);
      }
    }
    __builtin_amdgcn_s_setprio(0);

    bf16x8 pa[2];
#pragma unroll
    for (int rg = 0; rg < 2; rg++) {
      float pe[4], po[4];
#pragma unroll
      for (int r = 0; r < 4; r++) {
        pe[r] = __expf(sacc[rg][0][r] * scale);
        po[r] = __expf(sacc[rg][1][r] * scale);
      }
      den[rg] += (pe[0] + pe[1]) + (pe[2] + pe[3]) + (po[0] + po[1]) + (po[2] + po[3]);
      unsigned c0e = packbf(pe[0], pe[1]), c1e = packbf(pe[2], pe[3]);
      unsigned c0o = packbf(po[0], po[1]), c1o = packbf(po[2], po[3]);
      unsigned a0 = __shfl(c0e, srcA), a1 = __shfl(c0o, srcA);
      unsigned b0 = __shfl(c1e, srcA), b1 = __shfl(c1o, srcA);
      unsigned c0 = __shfl(c0e, srcB), c1 = __shfl(c0o, srcB);
      unsigned d0_ = __shfl(c1e, srcB), d1 = __shfl(c1o, srcB);
      uint4 paw;
      paw.x = hiSel ? a1 : a0;
      paw.y = hiSel ? b1 : b0;
      paw.z = hiSel ? c1 : c0;
      paw.w = hiSel ? d1 : d0_;
      pa[rg] = __builtin_bit_cast(bf16x8, paw);
    }

    char* vsb = (char*)&Vs[cur][0];
    __builtin_amdgcn_s_setprio(1);
#pragma unroll
    for (int d0 = 0; d0 < 8; d0++) {
      bf16x8 vf = ld_frag(vsb + (d0 * 16 + l15) * 80 + l4 * 16);
      oacc[0][d0] = __builtin_amdgcn_mfma_f32_16x16x32_bf16(pa[0], vf, oacc[0][d0], 0, 0, 0);
      oacc[1][d0] = __builtin_amdgcn_mfma_f32_16x16x32_bf16(pa[1], vf, oacc[1][d0], 0, 0, 0);
    }
    __builtin_amdgcn_s_setprio(0);

    if (t + 1 < 64) {
      char* ksn = (char*)&Ks[cur ^ 1][0];
      char* vsn = (char*)&Vs[cur ^ 1][0];
#pragma unroll
      for (int i = 0; i < 2; i++) {
        int kr = kr0 + i * 16;
        *(uint4*)(ksn + kr * 256 + ((kc ^ (kr & 7)) << 4)) = pk[i];
        int vr = vr0 + i * 64;
        *(uint4*)(vsn + vr * 80 + vc * 16) = pv[i];
      }
    }
  }

  // den: full sum for q-row l15 after xor-16/32; move to l4*4+r rows via shfl
  float dinv[2][4];
#pragma unroll
  for (int rg = 0; rg < 2; rg++) {
    float sd = den[rg];
    sd += __shfl_xor(sd, 16);
    sd += __shfl_xor(sd, 32);
#pragma unroll
    for (int r = 0; r < 4; r++) dinv[rg][r] = 1.0f / __shfl(sd, l4 * 4 + r);
  }
#pragma unroll
  for (int rg = 0; rg < 2; rg++)
#pragma unroll
    for (int d0 = 0; d0 < 8; d0++)
#pragma unroll
      for (int r = 0; r < 4; r++) {
        int token = b * LSEQ + q0 + wave * 32 + rg * 16 + l4 * 4 + r;
        Ao[(size_t)token * DM + h * HD + d0 * 16 + l15] =
            f2bf(oacc[rg][d0][r] * dinv[rg][r]);
      }
}

extern "C" void kernel_launch(void* const* d_in, const int* in_sizes, int n_in,
                              void* d_out, int out_size, void* d_ws, size_t ws_size,
                              hipStream_t stream) {
  const float* x  = (const float*)d_in[0];
  const float* Wq = (const float*)d_in[1];
  const float* bq = (const float*)d_in[2];
  const float* Wk = (const float*)d_in[3];
  const float* bk = (const float*)d_in[4];
  const float* Wv = (const float*)d_in[5];
  const float* bv = (const float*)d_in[6];
  const float* Wo = (const float*)d_in[7];
  const float* bo = (const float*)d_in[8];

  char* ws = (char*)d_ws;
  unsigned short* xb   = (unsigned short*)(ws + 0);          // [0,16M): x bf16 -> attn out
  unsigned short* wqkv = (unsigned short*)(ws + 16777216);   // [16M,40M): Wq|Wk|Wv bf16
  unsigned short* wob  = (unsigned short*)(ws + 41943040);   // [40M,48M): Wo bf16
  unsigned short* qkv  = (unsigned short*)(ws + 50364416);   // 48 MB region (q|k cols used)
  unsigned short* vt   = (unsigned short*)(ws + 100696064);  // 16.8 MB (transposed V)
  unsigned short* ao   = xb;                                  // x dead after QKV gemm

  // 1. all casts in one launch
  cvtall_k<<<12288, 256, 0, stream>>>(x, Wq, Wk, Wv, Wo, xb, wqkv, wob);

  // 2. fused QKV projection + q/k-norm + transposed V (768 blocks, 3.0 rounds)
  gemmv5_bt<1, 1><<<(MTOK / 128) * (QKVS / 256), 512, 0, stream>>>(
      xb, wqkv, bq, bk, bv, qkv, vt, MTOK, QKVS, DM);

  // 3. attention (full KV per block, grid 512, direct O)
  attn5_k<<<512, 256, 0, stream>>>(qkv, vt, ao);

  // 4. output projection (f32 out, 256 blocks = 1.0 round)
  gemmv5_bt<0, 0><<<(MTOK / 128) * (DM / 256), 512, 0, stream>>>(
      ao, wob, bo, bo, bo, (float*)d_out, nullptr, MTOK, DM, DM);
}